// Round 9
// baseline (592.944 us; speedup 1.0000x reference)
//
#include <hip/hip_runtime.h>
#include <hip/hip_bf16.h>

namespace {
constexpr int kB = 4;
constexpr int kN = 2048;
constexpr int kC = 1024;
constexpr int kH = 16;
constexpr int kD = 64;
constexpr float kScale = 0.125f;                    // 64^-0.5
constexpr float kC2 = 0.125f * 1.44269504088896f;   // kScale * log2(e)
}

typedef __attribute__((ext_vector_type(8))) short bf16x8;
typedef __attribute__((ext_vector_type(4))) float f32x4;

// ---- direct global->LDS DMA (m97 pattern). Linear dest: base + lane*16B. ----
#define ENABLE_GLDS 1
#if defined(__has_builtin)
#  if __has_builtin(__builtin_amdgcn_global_load_lds)
#    define HAVE_GLDS_BUILTIN 1
#  endif
#endif
#ifndef HAVE_GLDS_BUILTIN
#  define HAVE_GLDS_BUILTIN 0
#endif
#define USE_GLDS (ENABLE_GLDS && HAVE_GLDS_BUILTIN)

#if USE_GLDS
#define GLDS16(gp, lp)                                                  \
    __builtin_amdgcn_global_load_lds(                                   \
        (const __attribute__((address_space(1))) void*)(gp),            \
        (__attribute__((address_space(3))) void*)(lp), 16, 0, 0)
#endif

// ---------------------------------------------------------------------------
// bf16 split helpers: v = hi + lo with hi=RN(v), lo=RN(v-hi).
// ---------------------------------------------------------------------------
__device__ __forceinline__ unsigned short f2bf_rn(float x) {
    unsigned int u = __float_as_uint(x);
    u += 0x7FFFu + ((u >> 16) & 1u);   // round-to-nearest-even
    return (unsigned short)(u >> 16);
}
__device__ __forceinline__ float bf2f(unsigned short h) {
    return __uint_as_float((unsigned int)h << 16);
}

// ---------------------------------------------------------------------------
// Split-convert fp32 [rows][1024] -> bf16 [rows][3072], 8 elems/thread.
// btype=0 (A): [hi | hi | lo]; btype=1 (B): [hi | lo | hi].
// Paired dot over K'=3072 yields hi*hi + hi*lo + lo*hi (~fp32-exact GEMM).
// ---------------------------------------------------------------------------
__global__ __launch_bounds__(256) void split_kernel(
    const float* __restrict__ in, unsigned short* __restrict__ out,
    int total8, int btype)
{
    const int stride = gridDim.x * 256;
    for (int i = blockIdx.x * 256 + threadIdx.x; i < total8; i += stride) {
        const int r = i >> 7;            // 128 groups of 8 per 1024-row
        const int k8 = (i & 127) * 8;
        const float* src = in + (size_t)r * 1024 + k8;
        float a[8];
        *(float4*)&a[0] = *(const float4*)(src);
        *(float4*)&a[4] = *(const float4*)(src + 4);
        bf16x8 h8, l8;
        #pragma unroll
        for (int e = 0; e < 8; ++e) {
            const unsigned short hi = f2bf_rn(a[e]);
            h8[e] = (short)hi;
            l8[e] = (short)f2bf_rn(a[e] - bf2f(hi));
        }
        const size_t base = (size_t)r * 3072 + k8;
        *(bf16x8*)(out + base)        = h8;
        *(bf16x8*)(out + base + 1024) = btype ? l8 : h8;
        *(bf16x8*)(out + base + 2048) = btype ? h8 : l8;
    }
}

// ---------------------------------------------------------------------------
// bf16 MFMA GEMM, C[m][n] = sum_k A[m][k]*B[n][k] (row-major, K%32==0).
// m97 structure: 128x128 tile, BK=32, LINEAR LDS [128][32] (64B rows, no pad
// -- required by global_load_lds; b128 frag reads 8 words/bank = balanced),
// direct global->LDS DMA staging, 4 waves x 4x4 16x16x32 fragments.
// Wave w stages rows 32w..32w+31: lane i -> row 32w+(i>>2), k-slot (i&3)*8;
// DMA dest = wave-uniform base + i*16B == linear row-major (desk-verified).
// EPI=0: q -> fp32 [B,H,N,D]; k -> bf16 [B,H,N,D]; v -> bf16 [B,H,D,N]
//        (pre-transposed). region = bn>>10 is block-uniform (1024%128==0).
// EPI=1: out[b][n][o] = acc + bias[o] (fp32).
// ---------------------------------------------------------------------------
template<int EPI>
__global__ __launch_bounds__(256) void mfma_gemm_bt(
    const unsigned short* __restrict__ A,   // [M][Ktot]
    const unsigned short* __restrict__ Bm,  // [N][Ktot]
    const float* __restrict__ bias,
    float* __restrict__ o0, unsigned short* __restrict__ o1,
    unsigned short* __restrict__ o2, int Ktot)
{
    __shared__ __align__(16) unsigned short As[128 * 32];
    __shared__ __align__(16) unsigned short Bs[128 * 32];

    const int tid  = threadIdx.x;
    const int lane = tid & 63;
    const int wave = tid >> 6;
    const int wr = (wave >> 1) * 64;
    const int wc = (wave & 1) * 64;
    const int bm = blockIdx.x * 128;
    const int bn = blockIdx.y * 128;

    const int frow = lane & 15;         // A-row / B-row within fragment
    const int fks  = (lane >> 4) * 8;   // k-slice start

    f32x4 acc[4][4];
    #pragma unroll
    for (int i = 0; i < 4; ++i)
        #pragma unroll
        for (int j = 0; j < 4; ++j) acc[i][j] = (f32x4){0.f, 0.f, 0.f, 0.f};

    // staging: wave w covers LDS rows 32w..32w+31 (2 DMA / operand)
    const int sr = wave * 32 + (lane >> 2);   // global row for instr 0
    const int sk = (lane & 3) * 8;            // k-element offset
    const unsigned short* Ag0 = A + (size_t)(bm + sr) * Ktot + sk;
    const unsigned short* Ag1 = Ag0 + (size_t)16 * Ktot;
    const unsigned short* Bg0 = Bm + (size_t)(bn + sr) * Ktot + sk;
    const unsigned short* Bg1 = Bg0 + (size_t)16 * Ktot;
    unsigned short* AsD0 = &As[(wave * 32) * 32];
    unsigned short* AsD1 = &As[(wave * 32 + 16) * 32];
    unsigned short* BsD0 = &Bs[(wave * 32) * 32];
    unsigned short* BsD1 = &Bs[(wave * 32 + 16) * 32];

    for (int kt = 0; kt < Ktot; kt += 32) {
        __syncthreads();   // prev iter's LDS reads drained
#if USE_GLDS
        GLDS16(Ag0 + kt, AsD0);
        GLDS16(Ag1 + kt, AsD1);
        GLDS16(Bg0 + kt, BsD0);
        GLDS16(Bg1 + kt, BsD1);
#else
        *(float4*)(AsD0 + lane * 8) = *(const float4*)(Ag0 + kt);
        *(float4*)(AsD1 + lane * 8) = *(const float4*)(Ag1 + kt);
        *(float4*)(BsD0 + lane * 8) = *(const float4*)(Bg0 + kt);
        *(float4*)(BsD1 + lane * 8) = *(const float4*)(Bg1 + kt);
#endif
        __syncthreads();   // vmcnt(0) drained before barrier -> data ready

        bf16x8 af[4], bfr[4];
        #pragma unroll
        for (int i = 0; i < 4; ++i)
            af[i] = *(const bf16x8*)&As[(wr + i * 16 + frow) * 32 + fks];
        #pragma unroll
        for (int j = 0; j < 4; ++j)
            bfr[j] = *(const bf16x8*)&Bs[(wc + j * 16 + frow) * 32 + fks];
        #pragma unroll
        for (int i = 0; i < 4; ++i)
            #pragma unroll
            for (int j = 0; j < 4; ++j)
                acc[i][j] = __builtin_amdgcn_mfma_f32_16x16x32_bf16(
                    af[i], bfr[j], acc[i][j], 0, 0, 0);
    }

    // C/D layout: col = lane&15, row = (lane>>4)*4 + reg.
    const int crow = (lane >> 4) * 4;
    const int ccol = lane & 15;
    const int region = bn >> 10;   // EPI=0: 0=q, 1=k, 2=v (block-uniform)
    #pragma unroll
    for (int i = 0; i < 4; ++i) {
        #pragma unroll
        for (int r = 0; r < 4; ++r) {
            const int m = bm + wr + i * 16 + crow + r;
            const int b = m >> 11, n = m & 2047;
            #pragma unroll
            for (int j = 0; j < 4; ++j) {
                const int o = bn + wc + j * 16 + ccol;   // global output col
                const float val = acc[i][j][r];
                if (EPI == 0) {
                    const int cc = o & 1023;
                    const int h = cc >> 6, d = cc & 63;
                    if (region == 0)
                        o0[((size_t)(b * kH + h) * kN + n) * kD + d] = val;
                    else if (region == 1)
                        o1[((size_t)(b * kH + h) * kN + n) * kD + d] = f2bf_rn(val);
                    else
                        o2[((size_t)(b * kH + h) * kD + d) * kN + n] = f2bf_rn(val);
                } else {
                    o0[((size_t)b * kN + n) * kC + o] = val + bias[o];
                }
            }
        }
    }
}

// ---------------------------------------------------------------------------
// bf16 MFMA flash attention per (b,h). 64 q-rows/block, KV tiles of 64.
// Q-gate (q *= sigmoid(||q||)) fused into Q staging (width-4 shuffle norm).
// K arrives bf16 [B,H,N,D]; V arrives bf16 PRE-TRANSPOSED [B,H,D,N].
// T14 async-stage: tile t+1's global loads are issued right after tile t's
// LDS-publish barrier, hiding load latency under QK^T+softmax+PV.
// Softmax in exp2 domain (kScale*log2e folded); l kept as per-lane partial
// (fac is row-uniform -> linear recurrence commutes with lane-sum), reduced
// once in the epilogue. 4 waves; wave w owns S/O rows 16w..16w+15.
// LDS pitch 72 ushorts (144B): b128 frag reads/writes 8 words/bank balanced.
// Epilogue FUSES the proj-A split: writes hi/hi/lo bf16 into pout[8192][3072].
// ---------------------------------------------------------------------------
__global__ __launch_bounds__(256) void attn_mfma_kernel(
    const float* __restrict__ qb, const unsigned short* __restrict__ kb,
    const unsigned short* __restrict__ vbt, unsigned short* __restrict__ pout)
{
    __shared__ __align__(16) unsigned short Qs[64 * 72];
    __shared__ __align__(16) unsigned short Ks[64 * 72];   // [k-row][d]
    __shared__ __align__(16) unsigned short Vs[64 * 72];   // [d][k-in-tile]
    __shared__ __align__(16) unsigned short Ps[64 * 72];

    const int tid  = threadIdx.x;
    const int lane = tid & 63;
    const int wave = tid >> 6;          // 0..3
    const int qt = blockIdx.x;          // 0..31
    const int bh = blockIdx.y;          // 0..63

    const int srow = tid >> 2;          // 0..63 staging row
    const int sd   = (tid & 3) * 16;    // 0,16,32,48

    const float* Qg = qb + ((size_t)bh * kN + qt * 64) * kD;
    const unsigned short* Kg = kb + (size_t)bh * kN * kD;
    const unsigned short* Vg = vbt + (size_t)bh * kD * kN;

    // ---- stage Q with fused magnitude gate ----
    {
        const float* src = Qg + (size_t)srow * kD + sd;
        float arr[16];
        #pragma unroll
        for (int q = 0; q < 16; q += 4)
            *(float4*)&arr[q] = *(const float4*)(src + q);
        float ss = 0.f;
        #pragma unroll
        for (int q = 0; q < 16; ++q) ss = fmaf(arr[q], arr[q], ss);
        ss += __shfl_xor(ss, 1, 4);     // lanes tid&3 share row srow
        ss += __shfl_xor(ss, 2, 4);
        const float mag = sqrtf(ss);
        const float gate = 1.f / (1.f + __expf(-mag));
        bf16x8 q0, q1;
        #pragma unroll
        for (int e = 0; e < 8; ++e) {
            q0[e] = (short)f2bf_rn(arr[e] * gate);
            q1[e] = (short)f2bf_rn(arr[e + 8] * gate);
        }
        *(bf16x8*)&Qs[srow * 72 + sd]     = q0;
        *(bf16x8*)&Qs[srow * 72 + sd + 8] = q1;
    }
    __syncthreads();

    // Q fragments: lane holds Q[row=16w+(lane&15)][k=kc*32+(lane>>4)*8 ..+8]
    const int frow = lane & 15;
    const int fks  = (lane >> 4) * 8;
    bf16x8 qf[2];
    #pragma unroll
    for (int kc = 0; kc < 2; ++kc)
        qf[kc] = *(const bf16x8*)&Qs[(wave * 16 + frow) * 72 + kc * 32 + fks];

    const int g = lane >> 4;            // softmax row group
    float m2[4], l_r[4];                // m2 in log2 domain; l_r per-lane partial
    f32x4 o_acc[4];
    #pragma unroll
    for (int r = 0; r < 4; ++r) { m2[r] = -INFINITY; l_r[r] = 0.f; }
    #pragma unroll
    for (int j = 0; j < 4; ++j) o_acc[j] = (f32x4){0.f, 0.f, 0.f, 0.f};

    // ---- prologue: load tile 0 K/V into regs ----
    bf16x8 k0, k1, v0, v1;
    {
        const unsigned short* ksrc = Kg + (size_t)srow * kD + sd;
        const unsigned short* vsrc = Vg + (size_t)srow * kN + sd;
        k0 = *(const bf16x8*)(ksrc);
        k1 = *(const bf16x8*)(ksrc + 8);
        v0 = *(const bf16x8*)(vsrc);
        v1 = *(const bf16x8*)(vsrc + 8);
    }

    constexpr int kNT = kN / 64;
    for (int kt = 0; kt < kNT; ++kt) {
        __syncthreads();   // prev iter done reading Ks/Vs/Ps
        *(bf16x8*)&Ks[srow * 72 + sd]     = k0;
        *(bf16x8*)&Ks[srow * 72 + sd + 8] = k1;
        *(bf16x8*)&Vs[srow * 72 + sd]     = v0;
        *(bf16x8*)&Vs[srow * 72 + sd + 8] = v1;
        __syncthreads();

        // T14: issue next tile's loads now; latency hides under compute below
        if (kt + 1 < kNT) {
            const unsigned short* ksrc = Kg + (size_t)((kt + 1) * 64 + srow) * kD + sd;
            const unsigned short* vsrc = Vg + (size_t)srow * kN + (kt + 1) * 64 + sd;
            k0 = *(const bf16x8*)(ksrc);
            k1 = *(const bf16x8*)(ksrc + 8);
            v0 = *(const bf16x8*)(vsrc);
            v1 = *(const bf16x8*)(vsrc + 8);
        }

        // ---- S = Q K^T (wave's 16 rows x 64 cols) ----
        f32x4 s_acc[4];
        #pragma unroll
        for (int j = 0; j < 4; ++j) s_acc[j] = (f32x4){0.f, 0.f, 0.f, 0.f};
        #pragma unroll
        for (int j = 0; j < 4; ++j)
            #pragma unroll
            for (int kc = 0; kc < 2; ++kc) {
                const bf16x8 kf = *(const bf16x8*)&Ks[(j * 16 + frow) * 72 + kc * 32 + fks];
                s_acc[j] = __builtin_amdgcn_mfma_f32_16x16x32_bf16(qf[kc], kf, s_acc[j], 0, 0, 0);
            }

        // ---- online softmax, exp2 domain (row = 16w+4g+r) ----
        float mx[4], fac[4];
        #pragma unroll
        for (int r = 0; r < 4; ++r) {
            float v = fmaxf(fmaxf(s_acc[0][r], s_acc[1][r]), fmaxf(s_acc[2][r], s_acc[3][r]));
            mx[r] = v * kC2;
        }
        #pragma unroll
        for (int off = 1; off < 16; off <<= 1)
            #pragma unroll
            for (int r = 0; r < 4; ++r)
                mx[r] = fmaxf(mx[r], __shfl_xor(mx[r], off, 16));
        #pragma unroll
        for (int r = 0; r < 4; ++r) {
            const float mnew = fmaxf(m2[r], mx[r]);
            fac[r] = __builtin_exp2f(m2[r] - mnew);
            m2[r] = mnew;
        }
        float rs[4] = {0.f, 0.f, 0.f, 0.f};
        #pragma unroll
        for (int j = 0; j < 4; ++j)
            #pragma unroll
            for (int r = 0; r < 4; ++r) {
                const float p = __builtin_exp2f(fmaf(s_acc[j][r], kC2, -m2[r]));
                rs[r] += p;
                Ps[(wave * 16 + g * 4 + r) * 72 + j * 16 + frow] = f2bf_rn(p);
            }
        #pragma unroll
        for (int r = 0; r < 4; ++r) l_r[r] = l_r[r] * fac[r] + rs[r];  // per-lane partial
        #pragma unroll
        for (int j = 0; j < 4; ++j)
            #pragma unroll
            for (int r = 0; r < 4; ++r) o_acc[j][r] *= fac[r];
        __syncthreads();   // Ps visible to all lanes

        // ---- O += P V ----
        #pragma unroll
        for (int kc = 0; kc < 2; ++kc) {
            const bf16x8 pf = *(const bf16x8*)&Ps[(wave * 16 + frow) * 72 + kc * 32 + fks];
            #pragma unroll
            for (int j = 0; j < 4; ++j) {
                const bf16x8 vf = *(const bf16x8*)&Vs[(j * 16 + frow) * 72 + kc * 32 + fks];
                o_acc[j] = __builtin_amdgcn_mfma_f32_16x16x32_bf16(pf, vf, o_acc[j], 0, 0, 0);
            }
        }
    }

    // ---- epilogue: reduce l over 16-lane group, normalize + fused split ----
    float lt[4];
    #pragma unroll
    for (int r = 0; r < 4; ++r) {
        lt[r] = l_r[r];
        #pragma unroll
        for (int off = 1; off < 16; off <<= 1)
            lt[r] += __shfl_xor(lt[r], off, 16);
    }
    const int b = bh >> 4, h = bh & 15;
    #pragma unroll
    for (int r = 0; r < 4; ++r) {
        const float inv = 1.f / lt[r];
        const int n = qt * 64 + wave * 16 + g * 4 + r;
        const size_t mbase = ((size_t)b * kN + n) * 3072;
        #pragma unroll
        for (int j = 0; j < 4; ++j) {
            const int c = h * kD + j * 16 + frow;
            const float val = o_acc[j][r] * inv;
            const unsigned short hi = f2bf_rn(val);
            const unsigned short lo = f2bf_rn(val - bf2f(hi));
            pout[mbase + c]        = hi;
            pout[mbase + 1024 + c] = hi;
            pout[mbase + 2048 + c] = lo;
        }
    }
}

// ---------------------------------------------------------------------------
extern "C" void kernel_launch(void* const* d_in, const int* in_sizes, int n_in,
                              void* d_out, int out_size, void* d_ws, size_t ws_size,
                              hipStream_t stream)
{
    const float* x      = (const float*)d_in[0];
    const float* w_qkv  = (const float*)d_in[1];
    const float* w_proj = (const float*)d_in[2];
    const float* b_proj = (const float*)d_in[3];
    float* out = (float*)d_out;

    // Workspace (peak 130 MB):
    //   qb  @ 0     32MB fp32 [B,H,N,D]  (read-only in attn)
    //   kb  @ 32MB  16MB bf16 [B,H,N,D]
    //   vbt @ 48MB  16MB bf16 [B,H,D,N]  (pre-transposed V)
    //   Ab  @ 64MB  48MB bf16 [8192][3072] (x-split, then attn-out split)
    //   B1  @112MB  18MB bf16 weights' (w_proj split aliases: dead after gemm1)
    char* ws = (char*)d_ws;
    float* qb           = (float*)ws;
    unsigned short* kb  = (unsigned short*)(ws + 33554432);
    unsigned short* vbt = (unsigned short*)(ws + 50331648);
    unsigned short* Ab  = (unsigned short*)(ws + 67108864);
    unsigned short* B1  = (unsigned short*)(ws + 117440512);
    unsigned short* B2  = B1;   // stream-ordered reuse

    split_kernel<<<1024, 256, 0, stream>>>(x, Ab, kB * kN * kC / 8, 0);
    split_kernel<<<1024, 256, 0, stream>>>(w_qkv, B1, 3 * kC * kC / 8, 1);
    mfma_gemm_bt<0><<<dim3(64, 24), 256, 0, stream>>>(
        Ab, B1, nullptr, qb, kb, vbt, 3072);

    // q-gate fused into Q staging; proj-A split fused into epilogue
    attn_mfma_kernel<<<dim3(32, 64), 256, 0, stream>>>(qb, kb, vbt, Ab);

    split_kernel<<<512, 256, 0, stream>>>(w_proj, B2, kC * kC / 8, 1);
    mfma_gemm_bt<1><<<dim3(64, 8), 256, 0, stream>>>(
        Ab, B2, b_proj, out, nullptr, nullptr, 3072);
}